// Round 4
// baseline (857.767 us; speedup 1.0000x reference)
//
#include <hip/hip_runtime.h>
#include <cstdint>
#include <cstddef>

// (B,H,S,Dh) = (2, 8, 2048, 64), all float32 in/out.
#define BB 2
#define HH 8
#define SS 2048
#define DD 64
#define KP 128                    // bf16 hi|lo concatenated along k-dim
#define NQK (BB * HH * SS)        // q/k row count = 32768
#define NRH (BB * SS * HH)        // (b,row,h) triples = 32768
#define KVSTRIP 128               // kv per wave
#define KSPL (SS / KVSTRIP)       // 16 kv-split partial sums
#define CKV 16                    // kv per chunk
#define NCH (KVSTRIP / CKV)       // 8 chunks per wave

typedef short short8 __attribute__((ext_vector_type(8)));
typedef float f32x4  __attribute__((ext_vector_type(4)));
using u16 = unsigned short;
using u32 = unsigned int;
using u8  = unsigned char;

__device__ inline u16 bf16_rne(float f) {
  u32 u = __builtin_bit_cast(u32, f);
  u32 r = (u + 0x7FFFu + ((u >> 16) & 1u)) >> 16;
  return (u16)r;
}
__device__ inline float bf16_to_f(u16 h) {
  u32 u = ((u32)h) << 16;
  return __builtin_bit_cast(float, u);
}

// ---------------- K_mask: canonicalize mask -> u8[B*S] ---------------------
__global__ __launch_bounds__(256) void mask_canon(
    const void* __restrict__ maskg, u8* __restrict__ mc)
{
  __shared__ int sf, su;
  const int t = (int)threadIdx.x;
  if (t == 0) { sf = 0; su = 0; }
  __syncthreads();
  const u32* mw = (const u32*)maskg;
  int f = 0, u = 0;
  for (int i = t; i < 1024; i += 256) {   // 4KB scan: valid for all encodings
    u32 w = mw[i];
    if (w == 0x3F800000u) f = 1;
    if (w > 1u && w != 0x3F800000u) u = 1;
  }
  if (f) sf = 1;
  if (u) su = 1;
  __syncthreads();
  const int mode = sf ? 2 : (su ? 1 : 0);
  for (int i = t; i < BB * SS; i += 256) {
    u8 m;
    if (mode == 2)      m = (((const float*)maskg)[i] != 0.0f) ? 1 : 0;
    else if (mode == 1) m = (((const u8*)maskg)[i] != 0) ? 1 : 0;
    else                m = (((const int*)maskg)[i] != 0) ? 1 : 0;
    mc[i] = m;
  }
}

// ---------------- K0: f32 -> bf16 hi|lo (K=64 -> K=128) --------------------
__global__ __launch_bounds__(256) void convert_kernel(
    const float* __restrict__ q, const float* __restrict__ k,
    u16* __restrict__ qw, u16* __restrict__ kw)
{
  const int i   = (int)(blockIdx.x * 256 + threadIdx.x);  // float4 index
  const int row = i >> 4;
  const int c4  = (i & 15) << 2;

  const float4 qv = *(const float4*)(q + (size_t)i * 4);
  const float4 kv = *(const float4*)(k + (size_t)i * 4);

  u16 qh[4], ql[4], kh[4], kl[4];
  {
    const float qa[4] = {qv.x, qv.y, qv.z, qv.w};
    const float ka[4] = {kv.x, kv.y, kv.z, kv.w};
#pragma unroll
    for (int j = 0; j < 4; ++j) {
      qh[j] = bf16_rne(qa[j]);
      ql[j] = bf16_rne(qa[j] - bf16_to_f(qh[j]));
      kh[j] = bf16_rne(ka[j]);
      kl[j] = bf16_rne(ka[j] - bf16_to_f(kh[j]));
    }
  }
  uint2 qhi, qlo, khi, klo;
  qhi.x = (u32)qh[0] | ((u32)qh[1] << 16); qhi.y = (u32)qh[2] | ((u32)qh[3] << 16);
  qlo.x = (u32)ql[0] | ((u32)ql[1] << 16); qlo.y = (u32)ql[2] | ((u32)ql[3] << 16);
  khi.x = (u32)kh[0] | ((u32)kh[1] << 16); khi.y = (u32)kh[2] | ((u32)kh[3] << 16);
  klo.x = (u32)kl[0] | ((u32)kl[1] << 16); klo.y = (u32)kl[2] | ((u32)kl[3] << 16);

  const size_t base = (size_t)row * KP + c4;
  *(uint2*)(qw + base)      = qhi;
  *(uint2*)(qw + base + DD) = qlo;
  *(uint2*)(kw + base)      = khi;
  *(uint2*)(kw + base + DD) = klo;
}

// ---------------- K2: reduce kv-split partials -> inv[b][row][h] -----------
__global__ __launch_bounds__(256) void reduce_sums(
    const float* __restrict__ sums, float* __restrict__ invg)
{
  const int t = (int)(blockIdx.x * 256 + threadIdx.x);  // < NRH
  float s = 0.0f;
#pragma unroll
  for (int k = 0; k < KSPL; ++k) s += sums[(size_t)k * NRH + t];
  invg[t] = (s > 0.0f) ? (1.0f / s) : 0.0f;
}

// ---------------- attention body: all-heads-per-lane, no LDS ---------------
// Wave = 16 q-rows x 128-kv strip x all 8 heads. Lane (l4,l15) owns
// (row = l4*4+j, col = l15) for all h -> bias/inv are float4-contiguous in h.
template<int PHASE>
__device__ __forceinline__ void attn_body(
    const u16* __restrict__ qw, const u16* __restrict__ kw,
    const float* __restrict__ scaleg, const u8* __restrict__ maskc,
    const float* __restrict__ biasg, float* __restrict__ sums,
    const float* __restrict__ invg, float* __restrict__ outg)
{
  const int t    = (int)threadIdx.x;
  const int wid  = t >> 6;
  const int lane = t & 63;
  const int l15  = lane & 15;
  const int l4   = lane >> 4;

  // XCD swizzle: xcd = (b*32+qg)%8 so a (b,qg) group's qw slice stays in one L2
  const int bid = (int)blockIdx.x;
  const int x  = bid & 7;
  const int r  = bid >> 3;        // 0..127
  const int gp = r >> 4;          // 0..7
  const int ks = r & 15;
  const int g  = gp * 8 + x;      // 0..63 = b*32+qg
  const int b  = g >> 5;
  const int qg = g & 31;

  const int q0   = qg * 64 + wid * 16;
  const int kv0  = ks * KVSTRIP;
  const int rowj = q0 + l4 * 4;

  const float inv_scale = 1.0f / scaleg[0];
  const size_t hstr = (size_t)SS * KP;    // u16 per head plane

  const u16* qp0 = qw + ((size_t)b * HH * SS + q0 + l15) * KP + l4 * 8;
  const u16* kp0 = kw + ((size_t)b * HH * SS + kv0 + l15) * KP + l4 * 8;
  const float* bp0 = biasg + (((size_t)b * SS + rowj) * SS + kv0 + l15) * HH;
  const u8* mp = maskc + b * SS + kv0 + l15;
  float* ob = outg + (size_t)b * HH * SS * SS + (size_t)rowj * SS + kv0 + l15;

  f32x4 rsv[2][4];
  f32x4 invr[2][4];
  if (PHASE == 0) {
#pragma unroll
    for (int hf = 0; hf < 2; ++hf)
#pragma unroll
      for (int j = 0; j < 4; ++j) { f32x4 z = {0.f,0.f,0.f,0.f}; rsv[hf][j] = z; }
  } else {
#pragma unroll
    for (int hf = 0; hf < 2; ++hf)
#pragma unroll
      for (int j = 0; j < 4; ++j)
        invr[hf][j] = *(const f32x4*)(invg + ((size_t)b * SS + rowj + j) * HH + hf * 4);
  }

  for (int c = 0; c < NCH; ++c) {
    const float mzf = mp[c * CKV] ? 0.0f : 1.0f;

#pragma unroll
    for (int hf = 0; hf < 2; ++hf) {
      // bias for this half: float4 over h, per j  (issued before MFMA work)
      f32x4 bv[4];
#pragma unroll
      for (int j = 0; j < 4; ++j)
        bv[j] = *(const f32x4*)(bp0 + (size_t)j * (SS * HH) + c * (CKV * HH) + hf * 4);

      f32x4 a[4];
#pragma unroll
      for (int hh = 0; hh < 4; ++hh) {
        const int h = hf * 4 + hh;
        const u16* qp = qp0 + (size_t)h * hstr;
        const u16* kp = kp0 + (size_t)h * hstr + c * (CKV * KP);
        f32x4 acc = {0.f, 0.f, 0.f, 0.f};
#pragma unroll
        for (int kf = 0; kf < 4; ++kf) {
          const short8 af = *(const short8*)(qp + kf * 32);
          const short8 bf = *(const short8*)(kp + kf * 32);
          acc = __builtin_amdgcn_mfma_f32_16x16x32_bf16(af, bf, acc, 0, 0, 0);
        }
        a[hh] = acc;
      }

      // epilogue for this half
#pragma unroll
      for (int j = 0; j < 4; ++j) {
#pragma unroll
        for (int hh = 0; hh < 4; ++hh) {
          const float s = fmaf(a[hh][j], inv_scale, bv[j][hh]);
          const float w = mzf * __expf(s);
          if (PHASE == 0) {
            rsv[hf][j][hh] += w;
          } else {
            ob[(size_t)(hf * 4 + hh) * (SS * SS) + (size_t)j * SS + c * CKV] =
                w * invr[hf][j][hh];
          }
        }
      }
    }
  }

  if (PHASE == 0) {
#pragma unroll
    for (int hf = 0; hf < 2; ++hf)
#pragma unroll
      for (int j = 0; j < 4; ++j) {
        f32x4 v = rsv[hf][j];
#pragma unroll
        for (int hh = 0; hh < 4; ++hh) {
          float s = v[hh];
          s += __shfl_xor(s, 1, 64);
          s += __shfl_xor(s, 2, 64);
          s += __shfl_xor(s, 4, 64);
          s += __shfl_xor(s, 8, 64);
          v[hh] = s;
        }
        if (l15 == 0)
          *(f32x4*)(sums + (size_t)ks * NRH + ((size_t)b * SS + rowj + j) * HH + hf * 4) = v;
      }
  }
}

__global__ __launch_bounds__(256, 4) void attn_p0(
    const u16* __restrict__ qw, const u16* __restrict__ kw,
    const float* __restrict__ scaleg, const u8* __restrict__ maskc,
    const float* __restrict__ biasg, float* __restrict__ sums,
    const float* __restrict__ invg, float* __restrict__ outg)
{
  attn_body<0>(qw, kw, scaleg, maskc, biasg, sums, invg, outg);
}

__global__ __launch_bounds__(256, 3) void attn_p1(
    const u16* __restrict__ qw, const u16* __restrict__ kw,
    const float* __restrict__ scaleg, const u8* __restrict__ maskc,
    const float* __restrict__ biasg, float* __restrict__ sums,
    const float* __restrict__ invg, float* __restrict__ outg)
{
  attn_body<1>(qw, kw, scaleg, maskc, biasg, sums, invg, outg);
}

extern "C" void kernel_launch(void* const* d_in, const int* in_sizes, int n_in,
                              void* d_out, int out_size, void* d_ws, size_t ws_size,
                              hipStream_t stream) {
  const float* qg = (const float*)d_in[0];
  const float* kg = (const float*)d_in[1];
  const float* sc = (const float*)d_in[2];
  const void*  mk = d_in[3];
  const float* bg = (const float*)d_in[4];
  float* out = (float*)d_out;

  // workspace: qw 8MB | kw 8MB | sums 2MB | invg 128KB | maskc 4KB
  u16*   qw   = (u16*)d_ws;
  u16*   kw   = qw + (size_t)NQK * KP;
  float* sums = (float*)(kw + (size_t)NQK * KP);
  float* invg = sums + (size_t)KSPL * NRH;
  u8*    mcw  = (u8*)(invg + NRH);

  mask_canon<<<dim3(1), dim3(256), 0, stream>>>(mk, mcw);
  convert_kernel<<<dim3((NQK * (DD / 4)) / 256), dim3(256), 0, stream>>>(qg, kg, qw, kw);

  attn_p0<<<dim3(1024), dim3(256), 0, stream>>>(qw, kw, sc, mcw, bg, sums, invg, out);
  reduce_sums<<<dim3(NRH / 256), dim3(256), 0, stream>>>(sums, invg);
  attn_p1<<<dim3(1024), dim3(256), 0, stream>>>(qw, kw, sc, mcw, bg, sums, invg, out);
}

// Round 5
// 314.788 us; speedup vs baseline: 2.7249x; 2.7249x over previous
//
#include <hip/hip_runtime.h>
#include <cstdint>
#include <cstddef>

// (B,H,S,Dh) = (2, 8, 2048, 64), all float32 in/out.
#define BB 2
#define HH 8
#define SS 2048
#define DD 64
#define KP 128                 // bf16 hi|lo concatenated along k-dim
#define QT 32                  // q rows per WG
#define KSPLIT 8
#define KRANGE (SS / KSPLIT)   // 256 kv per WG
#define CKV 32                 // kv per chunk
#define NCH (KRANGE / CKV)     // 8 chunks
#define NROWS (BB * HH * SS)   // 32768 (b,h,row) triples

typedef short short8 __attribute__((ext_vector_type(8)));
typedef float f32x4  __attribute__((ext_vector_type(4)));
using u16 = unsigned short;
using u32 = unsigned int;
using u8  = unsigned char;

__device__ inline u16 bf16_rne(float f) {
  u32 u = __builtin_bit_cast(u32, f);
  u32 r = (u + 0x7FFFu + ((u >> 16) & 1u)) >> 16;
  return (u16)r;
}
__device__ inline float bf16_to_f(u16 h) {
  u32 u = ((u32)h) << 16;
  return __builtin_bit_cast(float, u);
}
__device__ inline u32 pack_bf16(float a, float b) {
  return (u32)bf16_rne(a) | ((u32)bf16_rne(b) << 16);
}

// ---------------- K_mask: canonicalize mask -> u8[B*S] ---------------------
__global__ __launch_bounds__(256) void mask_canon(
    const void* __restrict__ maskg, u8* __restrict__ mc)
{
  __shared__ int sf, su;
  const int t = (int)threadIdx.x;
  if (t == 0) { sf = 0; su = 0; }
  __syncthreads();
  const u32* mw = (const u32*)maskg;
  int f = 0, u = 0;
  for (int i = t; i < 1024; i += 256) {   // 4KB scan: valid for all encodings
    u32 w = mw[i];
    if (w == 0x3F800000u) f = 1;
    if (w > 1u && w != 0x3F800000u) u = 1;
  }
  if (f) sf = 1;
  if (u) su = 1;
  __syncthreads();
  const int mode = sf ? 2 : (su ? 1 : 0);
  for (int i = t; i < BB * SS; i += 256) {
    u8 m;
    if (mode == 2)      m = (((const float*)maskg)[i] != 0.0f) ? 1 : 0;
    else if (mode == 1) m = (((const u8*)maskg)[i] != 0) ? 1 : 0;
    else                m = (((const int*)maskg)[i] != 0) ? 1 : 0;
    mc[i] = m;
  }
}

// ---------------- K0: f32 -> bf16 hi|lo (K=64 -> K=128) --------------------
__global__ __launch_bounds__(256) void convert_kernel(
    const float* __restrict__ q, const float* __restrict__ k,
    u16* __restrict__ qw, u16* __restrict__ kw)
{
  const int i   = (int)(blockIdx.x * 256 + threadIdx.x);  // float4 index
  const int row = i >> 4;
  const int c4  = (i & 15) << 2;

  const float4 qv = *(const float4*)(q + (size_t)i * 4);
  const float4 kv = *(const float4*)(k + (size_t)i * 4);

  u16 qh[4], ql[4], kh[4], kl[4];
  {
    const float qa[4] = {qv.x, qv.y, qv.z, qv.w};
    const float ka[4] = {kv.x, kv.y, kv.z, kv.w};
#pragma unroll
    for (int j = 0; j < 4; ++j) {
      qh[j] = bf16_rne(qa[j]);
      ql[j] = bf16_rne(qa[j] - bf16_to_f(qh[j]));
      kh[j] = bf16_rne(ka[j]);
      kl[j] = bf16_rne(ka[j] - bf16_to_f(kh[j]));
    }
  }
  uint2 qhi, qlo, khi, klo;
  qhi.x = (u32)qh[0] | ((u32)qh[1] << 16); qhi.y = (u32)qh[2] | ((u32)qh[3] << 16);
  qlo.x = (u32)ql[0] | ((u32)ql[1] << 16); qlo.y = (u32)ql[2] | ((u32)ql[3] << 16);
  khi.x = (u32)kh[0] | ((u32)kh[1] << 16); khi.y = (u32)kh[2] | ((u32)kh[3] << 16);
  klo.x = (u32)kl[0] | ((u32)kl[1] << 16); klo.y = (u32)kl[2] | ((u32)kl[3] << 16);

  const size_t base = (size_t)row * KP + c4;
  *(uint2*)(qw + base)      = qhi;
  *(uint2*)(qw + base + DD) = qlo;
  *(uint2*)(kw + base)      = khi;
  *(uint2*)(kw + base + DD) = klo;
}

// ---------------- K2: reduce kv-split partials -> invg[b][h][row] ----------
__global__ __launch_bounds__(256) void reduce_sums(
    const float* __restrict__ sums, float* __restrict__ invg)
{
  const int t = (int)(blockIdx.x * 256 + threadIdx.x);  // < NROWS
  float s = 0.0f;
#pragma unroll
  for (int k = 0; k < KSPLIT; ++k) s += sums[(size_t)k * NROWS + t];
  invg[t] = (s > 0.0f) ? (1.0f / s) : 0.0f;
}

// ---------------- K1: MFMA scores + bias + exp -----------------------------
// WG = 512 = 8 waves = 8 heads, same (b, q-tile 32, kv-range 256).
// Bias double-buffered in LDS as packed bf16 (2 heads per u32):
//   s_b32[buf][h2][qr][kv^swz], 16 KB per buffer -> ONE barrier per chunk.
// Per chunk: k-loads -> MFMA -> stage next buffer -> prefetch c+2 -> epilogue.
// PHASE 0: accumulate partial row sums of w' = exp(qk/scale+bias) (0 masked).
// PHASE 1: recompute w', write w'*inv_row.
template<int PHASE>
__global__ __launch_bounds__(512, 4) void attn_kernel(
    const u16* __restrict__ qw, const u16* __restrict__ kw,
    const float* __restrict__ scaleg, const u8* __restrict__ maskc,
    const float* __restrict__ biasg, float* __restrict__ sums,
    const float* __restrict__ invg, float* __restrict__ outg)
{
  __shared__ u32 s_b32[2][4 * QT * CKV];   // 2 x 16 KB: [h2][qr][kv']
  __shared__ u8  s_mask[KRANGE];

  const int t    = (int)threadIdx.x;
  const int wid  = t >> 6;        // wave = head
  const int lane = t & 63;
  const int l15  = lane & 15;
  const int l4   = lane >> 4;

  const int bid = (int)blockIdx.x;
  const int b   = bid / ((SS / QT) * KSPLIT);
  const int rem = bid % ((SS / QT) * KSPLIT);
  const int q0     = (rem / KSPLIT) * QT;
  const int ks     = rem % KSPLIT;
  const int kvbase = ks * KRANGE;

  if (t < KRANGE) s_mask[t] = maskc[b * SS + kvbase + t];

  const float inv_scale = 1.0f / scaleg[0];
  const size_t bh = (size_t)(b * HH + wid);

  // ---- Q fragments (rows q0..q0+31, k = 0..127), hoisted ----
  short8 afr[2][4];
#pragma unroll
  for (int mi = 0; mi < 2; ++mi)
#pragma unroll
    for (int kf = 0; kf < 4; ++kf) {
      const int row = q0 + mi * 16 + l15;
      afr[mi][kf] = *(const short8*)(qw + (bh * SS + row) * KP + kf * 32 + (l4 << 3));
    }

  // ---- bias staging constants ----
  // thread stages rows qr = r*8+wid (r=0..3), kv = kvL, heads 4*hh..4*hh+3
  const int kvL = lane >> 1;              // 0..31
  const int hh  = lane & 1;               // h-half
  const int swz = ((wid >> 2) & 1) << 4;  // = ((qr>>2)&1)<<4 since qr=r*8+wid
  const int kv2 = kvL ^ swz;
  const float* bsrc0 = biasg +
      (((size_t)(b * SS + q0 + wid)) * SS + kvbase + kvL) * HH + hh * 4;
  const size_t bstep_r = (size_t)8 * SS * HH;   // +8 q-rows
  u32* sdst0 = &s_b32[0][(2 * hh) * (QT * CKV) + wid * CKV + kv2];

  float4 pre[4];
#pragma unroll
  for (int r = 0; r < 4; ++r)
    pre[r] = *(const float4*)(bsrc0 + (size_t)r * bstep_r);

  float rowsum[2][4];
  float invr[2][4];
  if (PHASE == 0) {
#pragma unroll
    for (int mi = 0; mi < 2; ++mi)
#pragma unroll
      for (int j = 0; j < 4; ++j) rowsum[mi][j] = 0.0f;
  } else {
#pragma unroll
    for (int mi = 0; mi < 2; ++mi)
#pragma unroll
      for (int j = 0; j < 4; ++j)
        invr[mi][j] = invg[bh * SS + (size_t)(q0 + mi * 16 + (l4 << 2) + j)];
  }

  // ---- prologue: stage chunk 0 into buf0, prefetch chunk 1 ----
#pragma unroll
  for (int r = 0; r < 4; ++r) {
    u32* d = sdst0 + r * (8 * CKV);
    d[0]         = pack_bf16(pre[r].x, pre[r].y);
    d[QT * CKV]  = pack_bf16(pre[r].z, pre[r].w);
  }
#pragma unroll
  for (int r = 0; r < 4; ++r)
    pre[r] = *(const float4*)(bsrc0 + (size_t)r * bstep_r + (CKV * HH));
  __syncthreads();   // buf0 + s_mask visible

  // per-lane epilogue LDS base (u16 index)
  const u16* sb_base = (const u16*)(&s_b32[0][0]);
  const int  sb_lane = ((wid >> 1) * (QT * CKV)) * 2 + (wid & 1);

  for (int c = 0; c < NCH; ++c) {
    const int p = c & 1;
    const int kv0c = kvbase + c * CKV;

    // ---- MFMA (k frags loaded per kf; compiler hoists under reg budget) ----
    f32x4 acc[2][2];
#pragma unroll
    for (int mi = 0; mi < 2; ++mi)
#pragma unroll
      for (int ni = 0; ni < 2; ++ni) {
        f32x4 z = {0.f, 0.f, 0.f, 0.f};
        acc[mi][ni] = z;
      }
#pragma unroll
    for (int kf = 0; kf < 4; ++kf) {
      short8 bfr[2];
#pragma unroll
      for (int ni = 0; ni < 2; ++ni) {
        const int col = kv0c + ni * 16 + l15;
        bfr[ni] = *(const short8*)(kw + (bh * SS + col) * KP + kf * 32 + (l4 << 3));
      }
#pragma unroll
      for (int mi = 0; mi < 2; ++mi)
#pragma unroll
        for (int ni = 0; ni < 2; ++ni)
          acc[mi][ni] = __builtin_amdgcn_mfma_f32_16x16x32_bf16(
              afr[mi][kf], bfr[ni], acc[mi][ni], 0, 0, 0);
    }

    // ---- stage chunk c+1 into buf[p^1] (overlaps MFMA drain) ----
    if (c + 1 < NCH) {
      u32* dst = sdst0 + (p ^ 1) * (4 * QT * CKV);
#pragma unroll
      for (int r = 0; r < 4; ++r) {
        u32* d = dst + r * (8 * CKV);
        d[0]        = pack_bf16(pre[r].x, pre[r].y);
        d[QT * CKV] = pack_bf16(pre[r].z, pre[r].w);
      }
    }
    // ---- prefetch bias for chunk c+2 ----
    if (c + 2 < NCH) {
#pragma unroll
      for (int r = 0; r < 4; ++r)
        pre[r] = *(const float4*)(bsrc0 + (size_t)r * bstep_r +
                                  (size_t)(c + 2) * (CKV * HH));
    }

    // ---- epilogue: bias(LDS bf16) + exp (+ mask) ----
    const u16* sb = sb_base + p * (4 * QT * CKV * 2);
#pragma unroll
    for (int ni = 0; ni < 2; ++ni) {
      const int kvloc = ni * 16 + l15;
      const float mz = s_mask[c * CKV + kvloc] ? 0.0f : 1.0f;
      const int kvx = kvloc ^ ((l4 & 1) << 4);
      const u32 colb = (u32)(kv0c + kvloc);
#pragma unroll
      for (int mi = 0; mi < 2; ++mi)
#pragma unroll
        for (int j = 0; j < 4; ++j) {
          const int qr = mi * 16 + (l4 << 2) + j;
          const u16 hv = sb[sb_lane + (qr * CKV + kvx) * 2];
          const float bv = bf16_to_f(hv);
          const float s  = fmaf(acc[mi][ni][j], inv_scale, bv);
          const float w  = mz * __expf(s);
          if (PHASE == 0) {
            rowsum[mi][j] += w;
          } else {
            const size_t o = (bh * SS + (size_t)(q0 + qr)) * SS + colb;
            outg[o] = w * invr[mi][j];
          }
        }
    }
    __syncthreads();   // buf[p^1] writes visible; buf[p] safe to overwrite
  }

  if (PHASE == 0) {
#pragma unroll
    for (int mi = 0; mi < 2; ++mi)
#pragma unroll
      for (int j = 0; j < 4; ++j) {
        float v = rowsum[mi][j];
        v += __shfl_xor(v, 1, 64);
        v += __shfl_xor(v, 2, 64);
        v += __shfl_xor(v, 4, 64);
        v += __shfl_xor(v, 8, 64);
        if (l15 == 0) {
          const int row = q0 + mi * 16 + (l4 << 2) + j;
          sums[(size_t)ks * NROWS + bh * SS + row] = v;
        }
      }
  }
}

extern "C" void kernel_launch(void* const* d_in, const int* in_sizes, int n_in,
                              void* d_out, int out_size, void* d_ws, size_t ws_size,
                              hipStream_t stream) {
  const float* qg = (const float*)d_in[0];
  const float* kg = (const float*)d_in[1];
  const float* sc = (const float*)d_in[2];
  const void*  mk = d_in[3];
  const float* bg = (const float*)d_in[4];
  float* out = (float*)d_out;

  // workspace: qw 8MB | kw 8MB | sums 1MB | invg 128KB | maskc 4KB
  u16*   qw   = (u16*)d_ws;
  u16*   kw   = qw + (size_t)NROWS * KP;
  float* sums = (float*)(kw + (size_t)NROWS * KP);
  float* invg = sums + (size_t)KSPLIT * NROWS;
  u8*    mcw  = (u8*)(invg + NROWS);

  mask_canon<<<dim3(1), dim3(256), 0, stream>>>(mk, mcw);
  convert_kernel<<<dim3((NROWS * (DD / 4)) / 256), dim3(256), 0, stream>>>(qg, kg, qw, kw);

  const int g1 = BB * (SS / QT) * KSPLIT;  // 1024 WGs
  attn_kernel<0><<<dim3(g1), dim3(512), 0, stream>>>(qw, kw, sc, mcw, bg, sums, invg, out);
  reduce_sums<<<dim3(NROWS / 256), dim3(256), 0, stream>>>(sums, invg);
  attn_kernel<1><<<dim3(g1), dim3(512), 0, stream>>>(qw, kw, sc, mcw, bg, sums, invg, out);
}

// Round 7
// 285.161 us; speedup vs baseline: 3.0080x; 1.1039x over previous
//
#include <hip/hip_runtime.h>
#include <cstdint>
#include <cstddef>

// (B,H,S,Dh) = (2, 8, 2048, 64), all float32 in/out.
#define BB 2
#define HH 8
#define SS 2048
#define DD 64
#define KP 128                 // bf16 hi|lo concatenated along k-dim
#define QT 32                  // q rows per WG
#define KSPLIT 8
#define KRANGE (SS / KSPLIT)   // 256 kv per WG
#define CKV 16                 // kv per chunk (one MFMA tile wide)
#define NCH (KRANGE / CKV)     // 16 chunks
#define NROWS (BB * HH * SS)   // 32768 (b,h,row) triples

typedef short short8 __attribute__((ext_vector_type(8)));
typedef float f32x4  __attribute__((ext_vector_type(4)));
using u16 = unsigned short;
using u32 = unsigned int;
using u8  = unsigned char;

__device__ inline u16 bf16_rne(float f) {
  u32 u = __builtin_bit_cast(u32, f);
  u32 r = (u + 0x7FFFu + ((u >> 16) & 1u)) >> 16;
  return (u16)r;
}
__device__ inline float bf16_to_f(u16 h) {
  u32 u = ((u32)h) << 16;
  return __builtin_bit_cast(float, u);
}
__device__ inline u32 pack_bf16(float a, float b) {
  return (u32)bf16_rne(a) | ((u32)bf16_rne(b) << 16);
}

// Barrier that drains ONLY the LDS queue (lgkmcnt) — the compiler's
// __syncthreads emits vmcnt(0) too, which would drain our in-flight HBM
// bias prefetch every chunk (m97 drain). sched_barrier(0) on both sides
// pins code motion (rule #18).
__device__ __forceinline__ void lds_barrier() {
  __builtin_amdgcn_sched_barrier(0);
  asm volatile("s_waitcnt lgkmcnt(0)" ::: "memory");
  __builtin_amdgcn_s_barrier();
  __builtin_amdgcn_sched_barrier(0);
}

// ---------------- K_mask: canonicalize mask -> u8[B*S] ---------------------
__global__ __launch_bounds__(256) void mask_canon(
    const void* __restrict__ maskg, u8* __restrict__ mc)
{
  __shared__ int sf, su;
  const int t = (int)threadIdx.x;
  if (t == 0) { sf = 0; su = 0; }
  __syncthreads();
  const u32* mw = (const u32*)maskg;
  int f = 0, u = 0;
  for (int i = t; i < 1024; i += 256) {   // 4KB scan: valid for all encodings
    u32 w = mw[i];
    if (w == 0x3F800000u) f = 1;
    if (w > 1u && w != 0x3F800000u) u = 1;
  }
  if (f) sf = 1;
  if (u) su = 1;
  __syncthreads();
  const int mode = sf ? 2 : (su ? 1 : 0);
  for (int i = t; i < BB * SS; i += 256) {
    u8 m;
    if (mode == 2)      m = (((const float*)maskg)[i] != 0.0f) ? 1 : 0;
    else if (mode == 1) m = (((const u8*)maskg)[i] != 0) ? 1 : 0;
    else                m = (((const int*)maskg)[i] != 0) ? 1 : 0;
    mc[i] = m;
  }
}

// ---------------- K0: f32 -> bf16 hi|lo (K=64 -> K=128) --------------------
__global__ __launch_bounds__(256) void convert_kernel(
    const float* __restrict__ q, const float* __restrict__ k,
    u16* __restrict__ qw, u16* __restrict__ kw)
{
  const int i   = (int)(blockIdx.x * 256 + threadIdx.x);  // float4 index
  const int row = i >> 4;
  const int c4  = (i & 15) << 2;

  const float4 qv = *(const float4*)(q + (size_t)i * 4);
  const float4 kv = *(const float4*)(k + (size_t)i * 4);

  u16 qh[4], ql[4], kh[4], kl[4];
  {
    const float qa[4] = {qv.x, qv.y, qv.z, qv.w};
    const float ka[4] = {kv.x, kv.y, kv.z, kv.w};
#pragma unroll
    for (int j = 0; j < 4; ++j) {
      qh[j] = bf16_rne(qa[j]);
      ql[j] = bf16_rne(qa[j] - bf16_to_f(qh[j]));
      kh[j] = bf16_rne(ka[j]);
      kl[j] = bf16_rne(ka[j] - bf16_to_f(kh[j]));
    }
  }

  uint2 qhi, qlo, khi, klo;
  qhi.x = (u32)qh[0] | ((u32)qh[1] << 16); qhi.y = (u32)qh[2] | ((u32)qh[3] << 16);
  qlo.x = (u32)ql[0] | ((u32)ql[1] << 16); qlo.y = (u32)ql[2] | ((u32)ql[3] << 16);
  khi.x = (u32)kh[0] | ((u32)kh[1] << 16); khi.y = (u32)kh[2] | ((u32)kh[3] << 16);
  klo.x = (u32)kl[0] | ((u32)kl[1] << 16); klo.y = (u32)kl[2] | ((u32)kl[3] << 16);

  const size_t base = (size_t)row * KP + c4;
  *(uint2*)(qw + base)      = qhi;
  *(uint2*)(qw + base + DD) = qlo;
  *(uint2*)(kw + base)      = khi;
  *(uint2*)(kw + base + DD) = klo;
}

// ---------------- K1: scores + bias + exp -> w' (unnormalized) -------------
// WG = 512 = 8 waves = 8 heads, same (b, q-tile 32, kv-range 256).
// Bias double-buffered in LDS as packed bf16 (2 heads per u32):
//   s_b32[buf][h2][qr][kv], 8 KB per buffer; ONE lgkm-only barrier per chunk;
//   HBM prefetch for chunk c+2 stays in flight across barriers.
__global__ __launch_bounds__(512, 4) void score_kernel(
    const u16* __restrict__ qw, const u16* __restrict__ kw,
    const float* __restrict__ scaleg, const u8* __restrict__ maskc,
    const float* __restrict__ biasg, float* __restrict__ outg)
{
  __shared__ u32 s_b32[2][4 * QT * CKV];   // 2 x 8 KB: [h2][qr][kv]
  __shared__ u8  s_mask[KRANGE];

  const int t    = (int)threadIdx.x;
  const int wid  = t >> 6;        // wave = head
  const int lane = t & 63;
  const int l15  = lane & 15;
  const int l4   = lane >> 4;

  const int bid = (int)blockIdx.x;
  const int b   = bid / ((SS / QT) * KSPLIT);
  const int rem = bid % ((SS / QT) * KSPLIT);
  const int q0     = (rem / KSPLIT) * QT;
  const int ks     = rem % KSPLIT;
  const int kvbase = ks * KRANGE;

  if (t < KRANGE) s_mask[t] = maskc[b * SS + kvbase + t];

  const float inv_scale = 1.0f / scaleg[0];
  const size_t bh = (size_t)(b * HH + wid);

  // ---- Q fragments (rows q0..q0+31, k = 0..127), hoisted ----
  short8 afr[2][4];
#pragma unroll
  for (int mi = 0; mi < 2; ++mi)
#pragma unroll
    for (int kf = 0; kf < 4; ++kf) {
      const int row = q0 + mi * 16 + l15;
      afr[mi][kf] = *(const short8*)(qw + (bh * SS + row) * KP + kf * 32 + (l4 << 3));
    }

  // ---- bias staging: thread t <-> (qr_s = t>>4, kv_s = t&15) ----
  // loads 2 float4 (heads 0-3, 4-7) per chunk; writes 4 u32 to planes 0..3.
  const int qr_s = t >> 4;
  const int kv_s = t & 15;
  const float* bsrc0 = biasg +
      (((size_t)(b * SS + q0 + qr_s)) * SS + kvbase + kv_s) * HH;
  u32* sdst0 = &s_b32[0][qr_s * CKV + kv_s];

  float4 pA = *(const float4*)(bsrc0);
  float4 pB = *(const float4*)(bsrc0 + 4);
  sdst0[0]             = pack_bf16(pA.x, pA.y);
  sdst0[QT * CKV]      = pack_bf16(pA.z, pA.w);
  sdst0[2 * QT * CKV]  = pack_bf16(pB.x, pB.y);
  sdst0[3 * QT * CKV]  = pack_bf16(pB.z, pB.w);
  pA = *(const float4*)(bsrc0 + CKV * HH);
  pB = *(const float4*)(bsrc0 + CKV * HH + 4);
  lds_barrier();   // buf0 + s_mask visible

  // epilogue read constants: plane = wid>>1, u16 half = wid&1
  const u16* sb_base = (const u16*)(&s_b32[0][0]);
  const int  sb_off  = ((wid >> 1) * (QT * CKV)) * 2 + (wid & 1);

  float* ob = outg + (bh * SS + (size_t)q0) * SS + kvbase + l15;

  for (int c = 0; c < NCH; ++c) {
    const int p = c & 1;
    const int kv0c = kvbase + c * CKV;

    // ---- MFMA: 16-wide kv tile, K=128 ----
    f32x4 acc[2];
    {
      f32x4 z = {0.f, 0.f, 0.f, 0.f};
      acc[0] = z; acc[1] = z;
    }
#pragma unroll
    for (int kf = 0; kf < 4; ++kf) {
      const short8 bfr = *(const short8*)(kw + (bh * SS + kv0c + l15) * KP +
                                          kf * 32 + (l4 << 3));
      acc[0] = __builtin_amdgcn_mfma_f32_16x16x32_bf16(afr[0][kf], bfr, acc[0], 0, 0, 0);
      acc[1] = __builtin_amdgcn_mfma_f32_16x16x32_bf16(afr[1][kf], bfr, acc[1], 0, 0, 0);
    }

    // ---- stage chunk c+1 into buf[p^1] ----
    if (c + 1 < NCH) {
      u32* d = sdst0 + (p ^ 1) * (4 * QT * CKV);
      d[0]             = pack_bf16(pA.x, pA.y);
      d[QT * CKV]      = pack_bf16(pA.z, pA.w);
      d[2 * QT * CKV]  = pack_bf16(pB.x, pB.y);
      d[3 * QT * CKV]  = pack_bf16(pB.z, pB.w);
    }
    // ---- prefetch bias for chunk c+2 (stays in flight across barrier) ----
    if (c + 2 < NCH) {
      pA = *(const float4*)(bsrc0 + (size_t)(c + 2) * (CKV * HH));
      pB = *(const float4*)(bsrc0 + (size_t)(c + 2) * (CKV * HH) + 4);
    }

    // ---- epilogue: bias(LDS bf16) + exp (+ mask), store w' ----
    const float mz = s_mask[c * CKV + l15] ? 0.0f : 1.0f;
    const u16* sb = sb_base + p * (4 * QT * CKV * 2) + sb_off;
#pragma unroll
    for (int mi = 0; mi < 2; ++mi)
#pragma unroll
      for (int j = 0; j < 4; ++j) {
        const int qr = mi * 16 + (l4 << 2) + j;
        const float bv = bf16_to_f(sb[(qr * CKV + l15) * 2]);
        const float s  = fmaf(acc[mi][j], inv_scale, bv);
        const float w  = mz * __expf(s);
        ob[(size_t)qr * SS + (size_t)(c * CKV)] = w;
      }
    lds_barrier();   // buf[p^1] visible; buf[p] reads retired
  }
}

// ---------------- K2: per-row normalize (in place, L3-hot) -----------------
// One wave per row of 2048 floats; 4 rows per 256-thread block.
__global__ __launch_bounds__(256, 4) void norm_kernel(float* __restrict__ outg)
{
  const int wave = (int)threadIdx.x >> 6;
  const int lane = (int)threadIdx.x & 63;
  const size_t row = (size_t)blockIdx.x * 4 + wave;   // < NROWS
  float4* p = (float4*)(outg + row * (size_t)SS);

  float4 v[8];
  float sum = 0.0f;
#pragma unroll
  for (int j = 0; j < 8; ++j) {
    v[j] = p[j * 64 + lane];
    sum += (v[j].x + v[j].y) + (v[j].z + v[j].w);
  }
#pragma unroll
  for (int off = 32; off > 0; off >>= 1) sum += __shfl_xor(sum, off, 64);

  const float inv = (sum > 0.0f) ? (1.0f / sum) : 0.0f;
#pragma unroll
  for (int j = 0; j < 8; ++j) {
    v[j].x *= inv; v[j].y *= inv; v[j].z *= inv; v[j].w *= inv;
    p[j * 64 + lane] = v[j];
  }
}

extern "C" void kernel_launch(void* const* d_in, const int* in_sizes, int n_in,
                              void* d_out, int out_size, void* d_ws, size_t ws_size,
                              hipStream_t stream) {
  const float* qg = (const float*)d_in[0];
  const float* kg = (const float*)d_in[1];
  const float* sc = (const float*)d_in[2];
  const void*  mk = d_in[3];
  const float* bg = (const float*)d_in[4];
  float* out = (float*)d_out;

  // workspace: qw 8MB | kw 8MB | maskc 4KB
  u16* qw  = (u16*)d_ws;
  u16* kw  = qw + (size_t)NROWS * KP;
  u8*  mcw = (u8*)(kw + (size_t)NROWS * KP);

  mask_canon<<<dim3(1), dim3(256), 0, stream>>>(mk, mcw);
  convert_kernel<<<dim3((NROWS * (DD / 4)) / 256), dim3(256), 0, stream>>>(qg, kg, qw, kw);

  const int g1 = BB * (SS / QT) * KSPLIT;  // 1024 WGs
  score_kernel<<<dim3(g1), dim3(512), 0, stream>>>(qw, kw, sc, mcw, bg, out);

  norm_kernel<<<dim3(NROWS / 4), dim3(256), 0, stream>>>(out);
}